// Round 4
// baseline (282.861 us; speedup 1.0000x reference)
//
#include <hip/hip_runtime.h>

#define N 96
#define NNN (N * N * N)
#define C_CH 32

// tile geometry: block 8x8x4 = 256 threads, each thread computes 4 voxels along w
#define TXD 8
#define TYD 8
#define TZD 4
#define VX 4
#define TW (TXD * VX)          // 32
#define TH TYD                 // 8
#define TD TZD                 // 4

// halo tile in LDS: 34 x 10 x 6, row padded to 35 (odd stride -> 2-way bank = free)
#define HWS 35
#define HH 10
#define HD 6
#define PLANE (HWS * HH)       // 350
#define HTOT (PLANE * HD)      // 2100
#define NTH (TXD * TYD * TZD)  // 256
#define NR ((HTOT + NTH - 1) / NTH)  // 9 staging rounds
#define SMSZ (NR * NTH)        // 2304 (over-allocated; pad words [2100,2304) never read)

// native clang vector for nontemporal builtin (HIP float4 is a class type)
typedef float vfloat4 __attribute__((ext_vector_type(4)));

__global__ __launch_bounds__(NTH, 2) void wincorr_kernel(
    const float* __restrict__ fixedp,
    const float* __restrict__ movingp,
    float* __restrict__ outp)
{
    // LDS double buffer + ONE raw barrier per channel (no vmcnt drain).
    // BRANCHLESS STAGING: loads are unconditional (OOB lanes load movingp[0]);
    // the select is on the LDS WRITE ADDRESS (channel-invariant, precomputed).
    // OOB lanes dump into a per-lane pad word that is never read; the truly-OOB
    // halo words are zeroed ONCE before the loop and never overwritten.
    // => no instruction touches the loaded register until the ds_write, so the
    // compiler's vmcnt wait is COUNTED at the consume site (T4), and the depth-2
    // prefetch genuinely stays in flight across the barrier.
    __shared__ float smA[SMSZ];
    __shared__ float smB[SMSZ];

    const int tx = threadIdx.x;   // 0..7  (w / 4)
    const int ty = threadIdx.y;   // 0..7  (h)
    const int tz = threadIdx.z;   // 0..3  (d)
    const int tid = tx + TXD * ty + TXD * TYD * tz;

    const int w0 = blockIdx.x * TW;
    const int h0 = blockIdx.y * TH;
    const int d0 = blockIdx.z * TD;

    // ---- channel-invariant staging addresses (global src + LDS dst) ----
    int off[NR];   // global word offset, clamped to 0 when OOB (always loadable)
    int lwa[NR];   // LDS word address: real slot, or per-lane dump word in pad
    #pragma unroll
    for (int r = 0; r < NR; ++r) {
        const int a = tid + r * NTH;
        const int z   = a / PLANE;
        const int rm  = a - z * PLANE;
        const int y   = rm / HWS;
        const int x   = rm - y * HWS;
        const int sd = d0 - 1 + z;
        const int sh = h0 - 1 + y;
        const int sw = w0 - 1 + x;
        const bool ok = (a < HTOT) && (x < TW + 2) &&
                        ((unsigned)sd < N) && ((unsigned)sh < N) && ((unsigned)sw < N);
        off[r] = ok ? ((sd * N + sh) * N + sw) : 0;
        lwa[r] = ok ? a : (HTOT + (tid & 63));   // dump: [2100, 2164) pad, per-lane
    }

    const int gw = w0 + VX * tx;
    const int fix_base = ((d0 + tz) * N + (h0 + ty)) * N + gw;
    const int lbase = tz * PLANE + ty * HWS + VX * tx;

    float acc[27][VX];
    #pragma unroll
    for (int s = 0; s < 27; ++s)
        #pragma unroll
        for (int v = 0; v < VX; ++v) acc[s][v] = 0.0f;

    // ---- prologue: issue depth-2 prefetch FIRST (HBM latency runs under init) ----
    float st0[NR], st1[NR];
    #pragma unroll
    for (int r = 0; r < NR; ++r) st0[r] = movingp[off[r]];
    {
        const float* m1 = movingp + (size_t)NNN;
        #pragma unroll
        for (int r = 0; r < NR; ++r) st1[r] = m1[off[r]];
    }
    float4 f0 = *(const float4*)&fixedp[fix_base];
    float4 f1 = *(const float4*)&fixedp[(size_t)NNN + fix_base];

    // zero both buffers (covers OOB halo words; staging never writes them again)
    #pragma unroll
    for (int r = 0; r < NR; ++r) {
        smA[tid + r * NTH] = 0.0f;
        smB[tid + r * NTH] = 0.0f;
    }
    __syncthreads();

    auto step = [&](int c, float* __restrict__ smw, float (&st)[NR], float4& f) {
        // commit channel c to LDS — the FIRST use of st's registers, so the
        // compiler emits a counted vmcnt here (c+1's loads remain outstanding)
        #pragma unroll
        for (int r = 0; r < NR; ++r)
            smw[lwa[r]] = st[r];

        // snapshot fixed operand before its registers are reissued
        const float fv[VX] = {f.x, f.y, f.z, f.w};

        // issue channel c+2 into the just-freed register set (clean loads, no
        // selects -> no wait at issue site)
        if (c + 2 < C_CH) {
            const float* mn = movingp + (size_t)(c + 2) * NNN;
            #pragma unroll
            for (int r = 0; r < NR; ++r) st[r] = mn[off[r]];
            f = *(const float4*)&fixedp[(size_t)(c + 2) * NNN + fix_base];
        }

        // LDS writes visible, raw barrier — global prefetch survives it
        asm volatile("s_waitcnt lgkmcnt(0)" ::: "memory");
        __builtin_amdgcn_s_barrier();
        asm volatile("" ::: "memory");

        // compute: 9 rows x 6-float sliding window, 27 taps x 4 voxels
        #pragma unroll
        for (int i = 0; i < 3; ++i) {
            #pragma unroll
            for (int j = 0; j < 3; ++j) {
                const float* row = &smw[lbase + i * PLANE + j * HWS];
                float wv[VX + 2];
                #pragma unroll
                for (int m = 0; m < VX + 2; ++m) wv[m] = row[m];
                #pragma unroll
                for (int k = 0; k < 3; ++k)
                    #pragma unroll
                    for (int v = 0; v < VX; ++v)
                        acc[(i * 3 + j) * 3 + k][v] += fv[v] * wv[v + k];
            }
        }
    };

    for (int c = 0; c < C_CH; c += 2) {
        step(c,     smA, st0, f0);
        step(c + 1, smB, st1, f1);
    }

    const float scale = 0.17677669529663687f; // 32^-0.5
    #pragma unroll
    for (int s = 0; s < 27; ++s) {
        vfloat4 o;
        o.x = acc[s][0] * scale;
        o.y = acc[s][1] * scale;
        o.z = acc[s][2] * scale;
        o.w = acc[s][3] * scale;
        // write-once output: nontemporal keeps the moving slab resident in L2
        __builtin_nontemporal_store(o, (vfloat4*)&outp[(size_t)s * NNN + fix_base]);
    }
}

extern "C" void kernel_launch(void* const* d_in, const int* in_sizes, int n_in,
                              void* d_out, int out_size, void* d_ws, size_t ws_size,
                              hipStream_t stream) {
    const float* fixedp  = (const float*)d_in[0];
    const float* movingp = (const float*)d_in[1];
    float* outp = (float*)d_out;

    dim3 block(TXD, TYD, TZD);                    // 8 x 8 x 4 = 256
    dim3 grid(N / TW, N / TH, N / TD);            // 3 x 12 x 24 = 864
    wincorr_kernel<<<grid, block, 0, stream>>>(fixedp, movingp, outp);
}